// Round 1
// baseline (1390.104 us; speedup 1.0000x reference)
//
#include <hip/hip_runtime.h>
#include <math.h>

#define N1 100000
#define N2 20000
#define N3 5000
#define EMB 128
#define NH 8

static constexpr float NEG = 0.2f;

// ---------------------------------------------------------------------------
// k_feat: gather h1 = item_emb[item_ids], compute fs0 = h1@W0, fs3 = h1@W3,
// attention dots el0 = (fs0*al0).sumDh, er0 = (fs0*ar0).sumDh, el3.
// One block = 16 nodes, 256 threads. Threads <128 own fs0 col j, >=128 own fs3.
// ---------------------------------------------------------------------------
__global__ __launch_bounds__(256) void k_feat(
    const float* __restrict__ item_emb, const int* __restrict__ item_ids,
    const float* __restrict__ fc_w, const float* __restrict__ attn_l,
    const float* __restrict__ attn_r,
    float* __restrict__ h1, float* __restrict__ fs0, float* __restrict__ fs3,
    float* __restrict__ el0, float* __restrict__ er0, float* __restrict__ el3)
{
    __shared__ float hs[16][EMB];       // 8 KB
    __shared__ float red[EMB * 17];     // 8.5 KB, padded stride 17

    const int tid = threadIdx.x;
    const int nbase = blockIdx.x * 16;

    // phase 1: gather 16 rows (512 float4), also write h1 out
    #pragma unroll
    for (int r = 0; r < 2; ++r) {
        int f4 = r * 256 + tid;         // 0..511
        int t  = f4 >> 5;               // node-in-tile
        int c4 = f4 & 31;               // float4 index in row
        int node = nbase + t;
        int row  = item_ids[node];
        float4 v = ((const float4*)(item_emb + (size_t)row * EMB))[c4];
        ((float4*)&hs[t][0])[c4] = v;
        ((float4*)(h1 + (size_t)node * EMB))[c4] = v;
    }
    __syncthreads();

    // phase 2: dual GEMM. j = output col; W0 for tid<128, W3 for tid>=128
    const int j = tid & 127;
    const float* W = fc_w + ((tid < 128) ? 0 : 3 * EMB * EMB);
    float acc[16];
    #pragma unroll
    for (int t = 0; t < 16; ++t) acc[t] = 0.f;

    for (int k = 0; k < EMB; k += 4) {
        float w0 = W[(k + 0) * EMB + j];
        float w1 = W[(k + 1) * EMB + j];
        float w2 = W[(k + 2) * EMB + j];
        float w3 = W[(k + 3) * EMB + j];
        #pragma unroll
        for (int t = 0; t < 16; ++t) {
            float4 h4 = *((const float4*)&hs[t][k]);   // broadcast read
            acc[t] = fmaf(h4.x, w0, fmaf(h4.y, w1,
                     fmaf(h4.z, w2, fmaf(h4.w, w3, acc[t]))));
        }
    }

    // store fs
    float* fsout = (tid < 128) ? fs0 : fs3;
    #pragma unroll
    for (int t = 0; t < 16; ++t)
        fsout[(size_t)(nbase + t) * EMB + j] = acc[t];

    // phase 3: attention dot reductions (per node, per head, sum over Dh=16)
    // round 1: el0 (fs0 * attn_l[0]);  round 2: er0; round 3: el3
    const float alv = (tid < 128) ? attn_l[j] : attn_l[3 * EMB + j];
    const float arv = (tid < 128) ? attn_r[j] : 0.f;

    // --- round 1: el0
    __syncthreads();
    if (tid < 128) {
        #pragma unroll
        for (int t = 0; t < 16; ++t) red[j * 17 + t] = acc[t] * alv;
    }
    __syncthreads();
    if (tid < 128) {
        int t = tid >> 3, h = tid & 7;
        float s = 0.f;
        #pragma unroll
        for (int d = 0; d < 16; ++d) s += red[(h * 16 + d) * 17 + t];
        el0[(size_t)(nbase + t) * NH + h] = s;
    }
    // --- round 2: er0
    __syncthreads();
    if (tid < 128) {
        #pragma unroll
        for (int t = 0; t < 16; ++t) red[j * 17 + t] = acc[t] * arv;
    }
    __syncthreads();
    if (tid < 128) {
        int t = tid >> 3, h = tid & 7;
        float s = 0.f;
        #pragma unroll
        for (int d = 0; d < 16; ++d) s += red[(h * 16 + d) * 17 + t];
        er0[(size_t)(nbase + t) * NH + h] = s;
    }
    // --- round 3: el3 (held by threads >=128)
    __syncthreads();
    if (tid >= 128) {
        #pragma unroll
        for (int t = 0; t < 16; ++t) red[j * 17 + t] = acc[t] * alv;
    }
    __syncthreads();
    if (tid < 128) {
        int t = tid >> 3, h = tid & 7;
        float s = 0.f;
        #pragma unroll
        for (int d = 0; d < 16; ++d) s += red[(h * 16 + d) * 17 + t];
        el3[(size_t)(nbase + t) * NH + h] = s;
    }
}

// ---------------------------------------------------------------------------
// k_edge: one wave (64 lanes) per edge. Accumulate denom[dst] += exp(e) and
// acc[dst] += exp(e) * fs[src] via atomics. No max pass (values bounded;
// alpha = exp(e)/sum(exp(e)) is invariant to the shift).
// has_er==0 -> er term is zero (dst features are zero).
// ---------------------------------------------------------------------------
__global__ __launch_bounds__(256) void k_edge(
    const int* __restrict__ src, const int* __restrict__ dst, int nE,
    const float* __restrict__ el, const float* __restrict__ er, int has_er,
    const float* __restrict__ fs,
    float* __restrict__ denom, float* __restrict__ acc)
{
    int wid  = (int)((blockIdx.x * blockDim.x + threadIdx.x) >> 6);
    int lane = threadIdx.x & 63;
    if (wid >= nE) return;
    int s = src[wid], d = dst[wid];
    int h = lane >> 3;
    float e = el[(size_t)s * NH + h];
    if (has_er) e += er[(size_t)d * NH + h];
    e = (e > 0.f) ? e : NEG * e;
    float w = expf(e);
    float2 f2 = ((const float2*)(fs + (size_t)s * EMB))[lane];
    float* ap = acc + (size_t)d * EMB + lane * 2;
    atomicAdd(ap + 0, w * f2.x);
    atomicAdd(ap + 1, w * f2.y);
    if ((lane & 7) == 0) atomicAdd(denom + (size_t)d * NH + h, w);
}

// ---------------------------------------------------------------------------
// k_out_mlp: assemble GAT output tile (normalize, residual, biases), then
// hidden MLP layer y = relu(x@W1 + b1), accumulate column sums into mean[].
// One block = 16 nodes, 256 threads (two half-groups of 8 nodes each).
// ---------------------------------------------------------------------------
__global__ __launch_bounds__(256) void k_out_mlp(
    const float* __restrict__ acc, const float* __restrict__ denom,
    const float* __restrict__ resid,            // h1 or nullptr
    const float* __restrict__ conv_b, int ia, int ib, int ic,
    const float* __restrict__ rw1, const float* __restrict__ rb1,
    float* __restrict__ mean)
{
    __shared__ float val[16][EMB];   // 8 KB
    const int tid = threadIdx.x;
    const int nbase = blockIdx.x * 16;

    // assembly
    #pragma unroll
    for (int r = 0; r < 8; ++r) {
        int idx = r * 256 + tid;
        int t = idx >> 7;
        int c = idx & 127;
        int node = nbase + t;
        int h = c >> 4;
        float dn = denom[(size_t)node * NH + h];
        float v = (dn > 0.f) ? acc[(size_t)node * EMB + c] / dn : 0.f;
        if (resid) v += resid[(size_t)node * EMB + c];
        v += conv_b[ia * EMB + c] + conv_b[ib * EMB + c];
        if (ic >= 0) v += conv_b[ic * EMB + c];
        val[t][c] = v;
    }
    __syncthreads();

    // hidden layer matvec: 8 nodes per thread
    const int j = tid & 127;
    const int half = tid >> 7;
    float a[8];
    #pragma unroll
    for (int t = 0; t < 8; ++t) a[t] = 0.f;
    for (int k = 0; k < EMB; k += 4) {
        float w0 = rw1[(k + 0) * EMB + j];
        float w1 = rw1[(k + 1) * EMB + j];
        float w2 = rw1[(k + 2) * EMB + j];
        float w3 = rw1[(k + 3) * EMB + j];
        #pragma unroll
        for (int t = 0; t < 8; ++t) {
            float4 h4 = *((const float4*)&val[half * 8 + t][k]);
            a[t] = fmaf(h4.x, w0, fmaf(h4.y, w1,
                   fmaf(h4.z, w2, fmaf(h4.w, w3, a[t]))));
        }
    }
    float b = rb1[j];
    float ysum = 0.f;
    #pragma unroll
    for (int t = 0; t < 8; ++t) ysum += fmaxf(a[t] + b, 0.f);
    atomicAdd(mean + j, ysum);
}

// ---------------------------------------------------------------------------
// k_final: second MLP layers (matvecs on the column means), constant-row
// readout for gran3, softmax weights, fused output.
// out layout: [0:128) fused | [128:512) stack rows | [512:515) weights
// ---------------------------------------------------------------------------
__global__ __launch_bounds__(128) void k_final(
    const float* __restrict__ mean1, const float* __restrict__ mean2,
    const float* __restrict__ conv_b,
    const float* __restrict__ r_w1, const float* __restrict__ r_b1,
    const float* __restrict__ r_w2, const float* __restrict__ r_b2,
    const float* __restrict__ gran_w, float* __restrict__ out)
{
    __shared__ float m1[EMB], m2[EMB], x3[EMB], t3[EMB];
    const int j = threadIdx.x;
    m1[j] = mean1[j] * (1.f / N1);
    m2[j] = mean2[j] * (1.f / N2);
    x3[j] = conv_b[2 * EMB + j] + conv_b[5 * EMB + j];
    __syncthreads();

    // gran3 hidden layer (single constant row)
    float a = r_b1[2 * EMB + j];
    for (int k = 0; k < EMB; ++k)
        a = fmaf(x3[k], r_w1[2 * EMB * EMB + k * EMB + j], a);
    t3[j] = fmaxf(a, 0.f);
    __syncthreads();

    float r1 = r_b2[0 * EMB + j];
    float r2 = r_b2[1 * EMB + j];
    float r3 = r_b2[2 * EMB + j];
    for (int k = 0; k < EMB; ++k) {
        r1 = fmaf(m1[k], r_w2[0 * EMB * EMB + k * EMB + j], r1);
        r2 = fmaf(m2[k], r_w2[1 * EMB * EMB + k * EMB + j], r2);
        r3 = fmaf(t3[k], r_w2[2 * EMB * EMB + k * EMB + j], r3);
    }

    float g0 = gran_w[0], g1 = gran_w[1], g2 = gran_w[2];
    float mx = fmaxf(g0, fmaxf(g1, g2));
    float e0 = expf(g0 - mx), e1 = expf(g1 - mx), e2 = expf(g2 - mx);
    float s = e0 + e1 + e2;
    float w0 = e0 / s, w1 = e1 / s, w2 = e2 / s;

    out[j]       = w0 * r1 + w1 * r2 + w2 * r3;  // fused
    out[128 + j] = r1;                            // stack row 0
    out[256 + j] = r2;                            // stack row 1
    out[384 + j] = r3;                            // stack row 2
    if (j < 3) out[512 + j] = (j == 0) ? w0 : (j == 1) ? w1 : w2;
}

extern "C" void kernel_launch(void* const* d_in, const int* in_sizes, int n_in,
                              void* d_out, int out_size, void* d_ws, size_t ws_size,
                              hipStream_t stream) {
    const int*   item_ids = (const int*)d_in[0];
    const int*   s1s = (const int*)d_in[1];
    const int*   s1d = (const int*)d_in[2];
    const int*   u1s = (const int*)d_in[7];
    const int*   u1d = (const int*)d_in[8];
    const float* item_emb = (const float*)d_in[15];
    const float* fc_w   = (const float*)d_in[16];
    const float* attn_l = (const float*)d_in[17];
    const float* attn_r = (const float*)d_in[18];
    const float* conv_b = (const float*)d_in[19];
    const float* r_w1 = (const float*)d_in[20];
    const float* r_b1 = (const float*)d_in[21];
    const float* r_w2 = (const float*)d_in[22];
    const float* r_b2 = (const float*)d_in[23];
    const float* gran_w = (const float*)d_in[24];

    const int nE1 = in_sizes[1];   // 600000
    const int nE3 = in_sizes[7];   // 200000

    float* ws = (float*)d_ws;
    // zeroed region first (one memset): acc0 | acc3 | denom0 | denom3 | means
    float* acc0   = ws;                              // N1*128
    float* acc3   = acc0 + (size_t)N1 * EMB;         // N2*128
    float* denom0 = acc3 + (size_t)N2 * EMB;         // N1*8
    float* denom3 = denom0 + (size_t)N1 * NH;        // N2*8
    float* mean1  = denom3 + (size_t)N2 * NH;        // 128
    float* mean2  = mean1 + EMB;                     // 128
    size_t zeroN  = (size_t)N1 * EMB + (size_t)N2 * EMB
                  + (size_t)N1 * NH + (size_t)N2 * NH + 2 * EMB;
    // non-zeroed scratch
    float* h1  = mean2 + EMB;                        // N1*128
    float* fs0 = h1  + (size_t)N1 * EMB;             // N1*128
    float* fs3 = fs0 + (size_t)N1 * EMB;             // N1*128
    float* el0 = fs3 + (size_t)N1 * EMB;             // N1*8
    float* er0 = el0 + (size_t)N1 * NH;              // N1*8
    float* el3 = er0 + (size_t)N1 * NH;              // N1*8

    hipMemsetAsync(ws, 0, zeroN * sizeof(float), stream);

    k_feat<<<N1 / 16, 256, 0, stream>>>(item_emb, item_ids, fc_w, attn_l, attn_r,
                                        h1, fs0, fs3, el0, er0, el3);

    k_edge<<<(nE1 + 3) / 4, 256, 0, stream>>>(s1s, s1d, nE1, el0, er0, 1,
                                              fs0, denom0, acc0);
    k_edge<<<(nE3 + 3) / 4, 256, 0, stream>>>(u1s, u1d, nE3, el3, nullptr, 0,
                                              fs3, denom3, acc3);

    // out1 = gat0(+resid h1) + b0 + b4 ; hidden MLP 0
    k_out_mlp<<<N1 / 16, 256, 0, stream>>>(acc0, denom0, h1, conv_b, 0, 4, -1,
                                           r_w1 + 0 * EMB * EMB, r_b1 + 0 * EMB,
                                           mean1);
    // out2 = gat3 + b3 + b1 + b6 ; hidden MLP 1
    k_out_mlp<<<N2 / 16, 256, 0, stream>>>(acc3, denom3, nullptr, conv_b, 3, 1, 6,
                                           r_w1 + 1 * EMB * EMB, r_b1 + 1 * EMB,
                                           mean2);

    k_final<<<1, 128, 0, stream>>>(mean1, mean2, conv_b, r_w1, r_b1, r_w2, r_b2,
                                   gran_w, (float*)d_out);
}

// Round 4
// 881.111 us; speedup vs baseline: 1.5777x; 1.5777x over previous
//
#include <hip/hip_runtime.h>
#include <math.h>

#define N1 100000
#define N2 20000
#define EMB 128
#define NH 8

static constexpr float NEG = 0.2f;

// ---------------------------------------------------------------------------
// k_feat: gather h1 = item_emb[item_ids], compute fs0 = h1@W0, fs3 = h1@W3,
// attention dots el0 = (fs0*al0).sumDh, er0 = (fs0*ar0).sumDh, el3.
// One block = 16 nodes, 256 threads. Threads <128 own fs0 col j, >=128 own fs3.
// ---------------------------------------------------------------------------
__global__ __launch_bounds__(256) void k_feat(
    const float* __restrict__ item_emb, const int* __restrict__ item_ids,
    const float* __restrict__ fc_w, const float* __restrict__ attn_l,
    const float* __restrict__ attn_r,
    float* __restrict__ h1, float* __restrict__ fs0, float* __restrict__ fs3,
    float* __restrict__ el0, float* __restrict__ er0, float* __restrict__ el3)
{
    __shared__ float hs[16][EMB];       // 8 KB
    __shared__ float red[EMB * 17];     // 8.5 KB, padded stride 17

    const int tid = threadIdx.x;
    const int nbase = blockIdx.x * 16;

    // phase 1: gather 16 rows (512 float4), also write h1 out
    #pragma unroll
    for (int r = 0; r < 2; ++r) {
        int f4 = r * 256 + tid;         // 0..511
        int t  = f4 >> 5;               // node-in-tile
        int c4 = f4 & 31;               // float4 index in row
        int node = nbase + t;
        int row  = item_ids[node];
        float4 v = ((const float4*)(item_emb + (size_t)row * EMB))[c4];
        ((float4*)&hs[t][0])[c4] = v;
        ((float4*)(h1 + (size_t)node * EMB))[c4] = v;
    }
    __syncthreads();

    // phase 2: dual GEMM. j = output col; W0 for tid<128, W3 for tid>=128
    const int j = tid & 127;
    const float* W = fc_w + ((tid < 128) ? 0 : 3 * EMB * EMB);
    float acc[16];
    #pragma unroll
    for (int t = 0; t < 16; ++t) acc[t] = 0.f;

    for (int k = 0; k < EMB; k += 4) {
        float w0 = W[(k + 0) * EMB + j];
        float w1 = W[(k + 1) * EMB + j];
        float w2 = W[(k + 2) * EMB + j];
        float w3 = W[(k + 3) * EMB + j];
        #pragma unroll
        for (int t = 0; t < 16; ++t) {
            float4 h4 = *((const float4*)&hs[t][k]);   // broadcast read
            acc[t] = fmaf(h4.x, w0, fmaf(h4.y, w1,
                     fmaf(h4.z, w2, fmaf(h4.w, w3, acc[t]))));
        }
    }

    // store fs
    float* fsout = (tid < 128) ? fs0 : fs3;
    #pragma unroll
    for (int t = 0; t < 16; ++t)
        fsout[(size_t)(nbase + t) * EMB + j] = acc[t];

    // phase 3: attention dot reductions (per node, per head, sum over Dh=16)
    const float alv = (tid < 128) ? attn_l[j] : attn_l[3 * EMB + j];
    const float arv = (tid < 128) ? attn_r[j] : 0.f;

    // --- round 1: el0
    __syncthreads();
    if (tid < 128) {
        #pragma unroll
        for (int t = 0; t < 16; ++t) red[j * 17 + t] = acc[t] * alv;
    }
    __syncthreads();
    if (tid < 128) {
        int t = tid >> 3, h = tid & 7;
        float s = 0.f;
        #pragma unroll
        for (int d = 0; d < 16; ++d) s += red[(h * 16 + d) * 17 + t];
        el0[(size_t)(nbase + t) * NH + h] = s;
    }
    // --- round 2: er0
    __syncthreads();
    if (tid < 128) {
        #pragma unroll
        for (int t = 0; t < 16; ++t) red[j * 17 + t] = acc[t] * arv;
    }
    __syncthreads();
    if (tid < 128) {
        int t = tid >> 3, h = tid & 7;
        float s = 0.f;
        #pragma unroll
        for (int d = 0; d < 16; ++d) s += red[(h * 16 + d) * 17 + t];
        er0[(size_t)(nbase + t) * NH + h] = s;
    }
    // --- round 3: el3 (held by threads >=128)
    __syncthreads();
    if (tid >= 128) {
        #pragma unroll
        for (int t = 0; t < 16; ++t) red[j * 17 + t] = acc[t] * alv;
    }
    __syncthreads();
    if (tid < 128) {
        int t = tid >> 3, h = tid & 7;
        float s = 0.f;
        #pragma unroll
        for (int d = 0; d < 16; ++d) s += red[(h * 16 + d) * 17 + t];
        el3[(size_t)(nbase + t) * NH + h] = s;
    }
}

// ---------------------------------------------------------------------------
// CSR build: count -> 3-kernel exclusive scan -> cursor scatter
// ---------------------------------------------------------------------------
__global__ __launch_bounds__(256) void k_count(
    const int* __restrict__ dst, int nE, int* __restrict__ cnt)
{
    int i = blockIdx.x * 256 + threadIdx.x;
    if (i < nE) atomicAdd(&cnt[dst[i]], 1);
}

__global__ __launch_bounds__(256) void k_scan_partial(
    const int* __restrict__ cnt, int n, int* __restrict__ part)
{
    __shared__ int sh[256];
    int base = blockIdx.x * 1024 + threadIdx.x * 4;
    int s = 0;
    #pragma unroll
    for (int k = 0; k < 4; ++k) { int i = base + k; if (i < n) s += cnt[i]; }
    sh[threadIdx.x] = s;
    __syncthreads();
    for (int off = 128; off > 0; off >>= 1) {
        if (threadIdx.x < off) sh[threadIdx.x] += sh[threadIdx.x + off];
        __syncthreads();
    }
    if (threadIdx.x == 0) part[blockIdx.x] = sh[0];
}

__global__ __launch_bounds__(256) void k_scan_mid(int* part, int np)
{
    __shared__ int sh[256];
    int tid = threadIdx.x;
    int v = (tid < np) ? part[tid] : 0;
    sh[tid] = v;
    __syncthreads();
    for (int off = 1; off < 256; off <<= 1) {
        int t = (tid >= off) ? sh[tid - off] : 0;
        __syncthreads();
        sh[tid] += t;
        __syncthreads();
    }
    if (tid < np) part[tid] = sh[tid] - v;   // exclusive
}

__global__ __launch_bounds__(256) void k_scan_final(
    const int* __restrict__ cnt, const int* __restrict__ part, int n, int nE,
    int* __restrict__ off, int* __restrict__ cur)
{
    __shared__ int sh[256];
    int tid = threadIdx.x;
    int base = blockIdx.x * 1024 + tid * 4;
    int c[4]; int s = 0;
    #pragma unroll
    for (int k = 0; k < 4; ++k) { int i = base + k; c[k] = (i < n) ? cnt[i] : 0; s += c[k]; }
    sh[tid] = s;
    __syncthreads();
    int own = s;
    for (int offv = 1; offv < 256; offv <<= 1) {
        int t = (tid >= offv) ? sh[tid - offv] : 0;
        __syncthreads();
        sh[tid] += t;
        __syncthreads();
    }
    int excl = sh[tid] - own + part[blockIdx.x];
    #pragma unroll
    for (int k = 0; k < 4; ++k) {
        int i = base + k;
        if (i < n) { off[i] = excl; cur[i] = excl; excl += c[k]; }
    }
    if (blockIdx.x == 0 && tid == 0) off[n] = nE;
}

__global__ __launch_bounds__(256) void k_scatter(
    const int* __restrict__ src, const int* __restrict__ dst, int nE,
    int* __restrict__ cur, int* __restrict__ esrc)
{
    int i = blockIdx.x * 256 + threadIdx.x;
    if (i < nE) {
        int pos = atomicAdd(&cur[dst[i]], 1);
        esrc[pos] = src[i];
    }
}

// ---------------------------------------------------------------------------
// k_aggregate: one wave per dst, lane owns 2 cols. Pull over CSR edges:
// acc += exp(leaky(el[src]+er[dst])) * fs[src], wsum += w. Write the fully
// assembled output row: acc/wsum (+resid) (+bias rows). Zero atomics.
// ---------------------------------------------------------------------------
__global__ __launch_bounds__(256) void k_aggregate(
    const int* __restrict__ off, const int* __restrict__ esrc,
    const float* __restrict__ el, const float* __restrict__ er,
    const float* __restrict__ fs, const float* __restrict__ resid,
    const float* __restrict__ conv_b, int ia, int ib, int ic,
    float* __restrict__ val)
{
    const int d = blockIdx.x * 4 + (threadIdx.x >> 6);
    const int lane = threadIdx.x & 63;
    const int h = lane >> 3;
    const int beg = off[d], end = off[d + 1];
    const float erh = er ? er[(size_t)d * NH + h] : 0.f;

    float ax = 0.f, ay = 0.f, wsum = 0.f;
    for (int base = beg; base < end; base += 64) {
        int myS = (base + lane < end) ? esrc[base + lane] : 0;  // coalesced
        int cnt = min(64, end - base);
        for (int i = 0; i < cnt; ++i) {
            int s = __shfl(myS, i);
            float e = el[(size_t)s * NH + h] + erh;
            e = (e > 0.f) ? e : NEG * e;
            float w = expf(e);
            float2 f2 = ((const float2*)(fs + (size_t)s * EMB))[lane];
            ax = fmaf(w, f2.x, ax);
            ay = fmaf(w, f2.y, ay);
            wsum += w;
        }
    }

    float vx = 0.f, vy = 0.f;
    if (end > beg) { float inv = 1.f / wsum; vx = ax * inv; vy = ay * inv; }
    if (resid) {
        float2 r = ((const float2*)(resid + (size_t)d * EMB))[lane];
        vx += r.x; vy += r.y;
    }
    const int c = lane * 2;
    float b0 = conv_b[ia * EMB + c]     + conv_b[ib * EMB + c];
    float b1 = conv_b[ia * EMB + c + 1] + conv_b[ib * EMB + c + 1];
    if (ic >= 0) { b0 += conv_b[ic * EMB + c]; b1 += conv_b[ic * EMB + c + 1]; }
    float2 o; o.x = vx + b0; o.y = vy + b1;
    ((float2*)(val + (size_t)d * EMB))[lane] = o;
}

// ---------------------------------------------------------------------------
// k_mlp: hidden layer y = relu(val@W1 + b1), accumulate column sums.
// One block = 16 nodes, 256 threads.
// ---------------------------------------------------------------------------
__global__ __launch_bounds__(256) void k_mlp(
    const float* __restrict__ val,
    const float* __restrict__ rw1, const float* __restrict__ rb1,
    float* __restrict__ mean)
{
    __shared__ float tile[16][EMB];   // 8 KB
    const int tid = threadIdx.x;
    const int nbase = blockIdx.x * 16;

    #pragma unroll
    for (int r = 0; r < 2; ++r) {
        int f4 = r * 256 + tid;
        int t  = f4 >> 5;
        int c4 = f4 & 31;
        ((float4*)&tile[t][0])[c4] =
            ((const float4*)(val + (size_t)(nbase + t) * EMB))[c4];
    }
    __syncthreads();

    const int j = tid & 127;
    const int half = tid >> 7;
    float a[8];
    #pragma unroll
    for (int t = 0; t < 8; ++t) a[t] = 0.f;
    for (int k = 0; k < EMB; k += 4) {
        float w0 = rw1[(k + 0) * EMB + j];
        float w1 = rw1[(k + 1) * EMB + j];
        float w2 = rw1[(k + 2) * EMB + j];
        float w3 = rw1[(k + 3) * EMB + j];
        #pragma unroll
        for (int t = 0; t < 8; ++t) {
            float4 h4 = *((const float4*)&tile[half * 8 + t][k]);
            a[t] = fmaf(h4.x, w0, fmaf(h4.y, w1,
                   fmaf(h4.z, w2, fmaf(h4.w, w3, a[t]))));
        }
    }
    float b = rb1[j];
    float ysum = 0.f;
    #pragma unroll
    for (int t = 0; t < 8; ++t) ysum += fmaxf(a[t] + b, 0.f);
    atomicAdd(mean + j, ysum);
}

// ---------------------------------------------------------------------------
// k_final: second MLP layers on the column means + constant gran3 row +
// softmax(gran_w) + fused output.
// ---------------------------------------------------------------------------
__global__ __launch_bounds__(128) void k_final(
    const float* __restrict__ mean1, const float* __restrict__ mean2,
    const float* __restrict__ conv_b,
    const float* __restrict__ r_w1, const float* __restrict__ r_b1,
    const float* __restrict__ r_w2, const float* __restrict__ r_b2,
    const float* __restrict__ gran_w, float* __restrict__ out)
{
    __shared__ float m1[EMB], m2[EMB], x3[EMB], t3[EMB];
    const int j = threadIdx.x;
    m1[j] = mean1[j] * (1.f / N1);
    m2[j] = mean2[j] * (1.f / N2);
    x3[j] = conv_b[2 * EMB + j] + conv_b[5 * EMB + j];
    __syncthreads();

    float a = r_b1[2 * EMB + j];
    for (int k = 0; k < EMB; ++k)
        a = fmaf(x3[k], r_w1[2 * EMB * EMB + k * EMB + j], a);
    t3[j] = fmaxf(a, 0.f);
    __syncthreads();

    float r1 = r_b2[0 * EMB + j];
    float r2 = r_b2[1 * EMB + j];
    float r3 = r_b2[2 * EMB + j];
    for (int k = 0; k < EMB; ++k) {
        r1 = fmaf(m1[k], r_w2[0 * EMB * EMB + k * EMB + j], r1);
        r2 = fmaf(m2[k], r_w2[1 * EMB * EMB + k * EMB + j], r2);
        r3 = fmaf(t3[k], r_w2[2 * EMB * EMB + k * EMB + j], r3);
    }

    float g0 = gran_w[0], g1 = gran_w[1], g2 = gran_w[2];
    float mx = fmaxf(g0, fmaxf(g1, g2));
    float e0 = expf(g0 - mx), e1 = expf(g1 - mx), e2 = expf(g2 - mx);
    float s = e0 + e1 + e2;
    float w0 = e0 / s, w1 = e1 / s, w2 = e2 / s;

    out[j]       = w0 * r1 + w1 * r2 + w2 * r3;
    out[128 + j] = r1;
    out[256 + j] = r2;
    out[384 + j] = r3;
    if (j < 3) out[512 + j] = (j == 0) ? w0 : (j == 1) ? w1 : w2;
}

extern "C" void kernel_launch(void* const* d_in, const int* in_sizes, int n_in,
                              void* d_out, int out_size, void* d_ws, size_t ws_size,
                              hipStream_t stream) {
    const int*   item_ids = (const int*)d_in[0];
    const int*   s1s = (const int*)d_in[1];
    const int*   s1d = (const int*)d_in[2];
    const int*   u1s = (const int*)d_in[7];
    const int*   u1d = (const int*)d_in[8];
    const float* item_emb = (const float*)d_in[15];
    const float* fc_w   = (const float*)d_in[16];
    const float* attn_l = (const float*)d_in[17];
    const float* attn_r = (const float*)d_in[18];
    const float* conv_b = (const float*)d_in[19];
    const float* r_w1 = (const float*)d_in[20];
    const float* r_b1 = (const float*)d_in[21];
    const float* r_w2 = (const float*)d_in[22];
    const float* r_b2 = (const float*)d_in[23];
    const float* gran_w = (const float*)d_in[24];

    const int nE1 = in_sizes[1];   // 600000
    const int nE3 = in_sizes[7];   // 200000

    float* ws = (float*)d_ws;
    // --- zero region (one memset): mean1 | mean2 | cnt1 | cnt2
    float* mean1 = ws;
    float* mean2 = mean1 + EMB;
    int*   cnt1  = (int*)(mean2 + EMB);
    int*   cnt2  = cnt1 + N1;
    size_t zeroN = 2 * EMB + N1 + N2;
    // --- non-zeroed scratch
    int*   off1  = cnt2 + N2;            // N1+1
    int*   cur1  = off1 + N1 + 1;        // N1
    int*   off2  = cur1 + N1;            // N2+1
    int*   cur2  = off2 + N2 + 1;        // N2
    int*   part1 = cur2 + N2;            // 128
    int*   part2 = part1 + 128;          // 128
    int*   esrc1 = part2 + 128;          // nE1
    int*   esrc2 = esrc1 + nE1;          // nE3
    float* h1   = (float*)(esrc2 + nE3); // N1*128
    float* fs0  = h1  + (size_t)N1 * EMB;
    float* fs3  = fs0 + (size_t)N1 * EMB;
    float* el0  = fs3 + (size_t)N1 * EMB;  // N1*8
    float* er0  = el0 + (size_t)N1 * NH;
    float* el3  = er0 + (size_t)N1 * NH;
    float* val1 = el3 + (size_t)N1 * NH;   // N1*128
    float* val2 = val1 + (size_t)N1 * EMB; // N2*128

    hipMemsetAsync(ws, 0, zeroN * sizeof(float), stream);

    // features + attention dots
    k_feat<<<N1 / 16, 256, 0, stream>>>(item_emb, item_ids, fc_w, attn_l, attn_r,
                                        h1, fs0, fs3, el0, er0, el3);

    // CSR build, graph seq1 (dst domain N1)
    const int nch1 = (N1 + 1023) / 1024;   // 98
    k_count<<<(nE1 + 255) / 256, 256, 0, stream>>>(s1d, nE1, cnt1);
    k_scan_partial<<<nch1, 256, 0, stream>>>(cnt1, N1, part1);
    k_scan_mid<<<1, 256, 0, stream>>>(part1, nch1);
    k_scan_final<<<nch1, 256, 0, stream>>>(cnt1, part1, N1, nE1, off1, cur1);
    k_scatter<<<(nE1 + 255) / 256, 256, 0, stream>>>(s1s, s1d, nE1, cur1, esrc1);

    // CSR build, graph up1 (dst domain N2)
    const int nch2 = (N2 + 1023) / 1024;   // 20
    k_count<<<(nE3 + 255) / 256, 256, 0, stream>>>(u1d, nE3, cnt2);
    k_scan_partial<<<nch2, 256, 0, stream>>>(cnt2, N2, part2);
    k_scan_mid<<<1, 256, 0, stream>>>(part2, nch2);
    k_scan_final<<<nch2, 256, 0, stream>>>(cnt2, part2, N2, nE3, off2, cur2);
    k_scatter<<<(nE3 + 255) / 256, 256, 0, stream>>>(u1s, u1d, nE3, cur2, esrc2);

    // pull aggregation (writes fully assembled rows)
    k_aggregate<<<N1 / 4, 256, 0, stream>>>(off1, esrc1, el0, er0, fs0, h1,
                                            conv_b, 0, 4, -1, val1);
    k_aggregate<<<N2 / 4, 256, 0, stream>>>(off2, esrc2, el3, nullptr, fs3, nullptr,
                                            conv_b, 3, 1, 6, val2);

    // hidden MLP + column-sum reduction
    k_mlp<<<N1 / 16, 256, 0, stream>>>(val1, r_w1 + 0 * EMB * EMB, r_b1 + 0 * EMB, mean1);
    k_mlp<<<N2 / 16, 256, 0, stream>>>(val2, r_w1 + 1 * EMB * EMB, r_b1 + 1 * EMB, mean2);

    k_final<<<1, 128, 0, stream>>>(mean1, mean2, conv_b, r_w1, r_b1, r_w2, r_b2,
                                   gran_w, (float*)d_out);
}

// Round 5
// 585.160 us; speedup vs baseline: 2.3756x; 1.5058x over previous
//
#include <hip/hip_runtime.h>
#include <math.h>

#define N1 100000
#define N2 20000
#define EMB 128
#define NH 8
#define TILE 64
#define LPAD 132   // LDS row pitch (floats): 132 ≡ 4 (mod 32) banks, 16B-aligned

static constexpr float NEG = 0.2f;

// ---------------------------------------------------------------------------
// k_feat64: gather h1 = item_emb[item_ids] into LDS (64-row tile), dual GEMM
// fs0 = h1@W0, fs3 = h1@W3 with 8x4 register tiling, and fused attention-dot
// epilogue (el0/er0/el3) via 4-lane shfl reduction per head.
// 256 threads: cg = tid&31 owns cols 4cg..4cg+3, rg = tid>>5 owns rows 8rg..+7.
// ---------------------------------------------------------------------------
__global__ __launch_bounds__(256) void k_feat64(
    const float* __restrict__ item_emb, const int* __restrict__ item_ids,
    const float* __restrict__ fc_w, const float* __restrict__ attn_l,
    const float* __restrict__ attn_r,
    float* __restrict__ h1, float* __restrict__ fs0, float* __restrict__ fs3,
    float* __restrict__ el0, float* __restrict__ er0, float* __restrict__ el3)
{
    __shared__ float xs[TILE][LPAD];   // 33 KB

    const int tid = threadIdx.x;
    const int nbase = blockIdx.x * TILE;

    // gather: 64 rows x 32 float4 = 2048 float4, 8 per thread
    #pragma unroll
    for (int r = 0; r < 8; ++r) {
        int f4 = r * 256 + tid;
        int t  = f4 >> 5;
        int c4 = f4 & 31;
        int node = nbase + t;
        if (node < N1) {
            int row = item_ids[node];
            float4 v = ((const float4*)(item_emb + (size_t)row * EMB))[c4];
            ((float4*)&xs[t][0])[c4] = v;
            ((float4*)(h1 + (size_t)node * EMB))[c4] = v;
        }
    }
    __syncthreads();

    const int cg = tid & 31;
    const int rg = tid >> 5;
    const int j0 = cg * 4;
    const float* W0 = fc_w + j0;
    const float* W3 = fc_w + 3 * EMB * EMB + j0;

    float a0[8][4], a3[8][4];
    #pragma unroll
    for (int r = 0; r < 8; ++r)
        #pragma unroll
        for (int c = 0; c < 4; ++c) { a0[r][c] = 0.f; a3[r][c] = 0.f; }

    for (int k = 0; k < EMB; k += 4) {
        float w0v[4][4], w3v[4][4];
        #pragma unroll
        for (int kk = 0; kk < 4; ++kk) {
            float4 t0 = *((const float4*)(W0 + (size_t)(k + kk) * EMB));
            float4 t3 = *((const float4*)(W3 + (size_t)(k + kk) * EMB));
            w0v[kk][0] = t0.x; w0v[kk][1] = t0.y; w0v[kk][2] = t0.z; w0v[kk][3] = t0.w;
            w3v[kk][0] = t3.x; w3v[kk][1] = t3.y; w3v[kk][2] = t3.z; w3v[kk][3] = t3.w;
        }
        #pragma unroll
        for (int r = 0; r < 8; ++r) {
            float4 x = *((const float4*)&xs[rg * 8 + r][k]);
            #pragma unroll
            for (int c = 0; c < 4; ++c) {
                a0[r][c] = fmaf(x.x, w0v[0][c], a0[r][c]);
                a0[r][c] = fmaf(x.y, w0v[1][c], a0[r][c]);
                a0[r][c] = fmaf(x.z, w0v[2][c], a0[r][c]);
                a0[r][c] = fmaf(x.w, w0v[3][c], a0[r][c]);
                a3[r][c] = fmaf(x.x, w3v[0][c], a3[r][c]);
                a3[r][c] = fmaf(x.y, w3v[1][c], a3[r][c]);
                a3[r][c] = fmaf(x.z, w3v[2][c], a3[r][c]);
                a3[r][c] = fmaf(x.w, w3v[3][c], a3[r][c]);
            }
        }
    }

    // store fs tiles
    #pragma unroll
    for (int r = 0; r < 8; ++r) {
        int row = nbase + rg * 8 + r;
        if (row < N1) {
            float4 v0 = make_float4(a0[r][0], a0[r][1], a0[r][2], a0[r][3]);
            float4 v3 = make_float4(a3[r][0], a3[r][1], a3[r][2], a3[r][3]);
            *((float4*)(fs0 + (size_t)row * EMB + j0)) = v0;
            *((float4*)(fs3 + (size_t)row * EMB + j0)) = v3;
        }
    }

    // fused attention dots: head = j0>>4 (4 col-threads per head; lanes
    // differing in tid bits 0-1 -> shfl_xor 1,2 completes the 16-col dot)
    float al0v[4], ar0v[4], al3v[4];
    #pragma unroll
    for (int c = 0; c < 4; ++c) {
        al0v[c] = attn_l[j0 + c];
        ar0v[c] = attn_r[j0 + c];
        al3v[c] = attn_l[3 * EMB + j0 + c];
    }
    const int head = j0 >> 4;
    #pragma unroll
    for (int r = 0; r < 8; ++r) {
        float pe = a0[r][0]*al0v[0] + a0[r][1]*al0v[1] + a0[r][2]*al0v[2] + a0[r][3]*al0v[3];
        float pr = a0[r][0]*ar0v[0] + a0[r][1]*ar0v[1] + a0[r][2]*ar0v[2] + a0[r][3]*ar0v[3];
        float p3 = a3[r][0]*al3v[0] + a3[r][1]*al3v[1] + a3[r][2]*al3v[2] + a3[r][3]*al3v[3];
        pe += __shfl_xor(pe, 1); pe += __shfl_xor(pe, 2);
        pr += __shfl_xor(pr, 1); pr += __shfl_xor(pr, 2);
        p3 += __shfl_xor(p3, 1); p3 += __shfl_xor(p3, 2);
        int row = nbase + rg * 8 + r;
        if ((cg & 3) == 0 && row < N1) {
            el0[(size_t)row * NH + head] = pe;
            er0[(size_t)row * NH + head] = pr;
            el3[(size_t)row * NH + head] = p3;
        }
    }
}

// ---------------------------------------------------------------------------
// CSR build: count -> 3-kernel exclusive scan -> cursor scatter
// ---------------------------------------------------------------------------
__global__ __launch_bounds__(256) void k_count(
    const int* __restrict__ dst, int nE, int* __restrict__ cnt)
{
    int i = blockIdx.x * 256 + threadIdx.x;
    if (i < nE) atomicAdd(&cnt[dst[i]], 1);
}

__global__ __launch_bounds__(256) void k_scan_partial(
    const int* __restrict__ cnt, int n, int* __restrict__ part)
{
    __shared__ int sh[256];
    int base = blockIdx.x * 1024 + threadIdx.x * 4;
    int s = 0;
    #pragma unroll
    for (int k = 0; k < 4; ++k) { int i = base + k; if (i < n) s += cnt[i]; }
    sh[threadIdx.x] = s;
    __syncthreads();
    for (int off = 128; off > 0; off >>= 1) {
        if (threadIdx.x < off) sh[threadIdx.x] += sh[threadIdx.x + off];
        __syncthreads();
    }
    if (threadIdx.x == 0) part[blockIdx.x] = sh[0];
}

__global__ __launch_bounds__(256) void k_scan_mid(int* part, int np)
{
    __shared__ int sh[256];
    int tid = threadIdx.x;
    int v = (tid < np) ? part[tid] : 0;
    sh[tid] = v;
    __syncthreads();
    for (int off = 1; off < 256; off <<= 1) {
        int t = (tid >= off) ? sh[tid - off] : 0;
        __syncthreads();
        sh[tid] += t;
        __syncthreads();
    }
    if (tid < np) part[tid] = sh[tid] - v;   // exclusive
}

__global__ __launch_bounds__(256) void k_scan_final(
    const int* __restrict__ cnt, const int* __restrict__ part, int n, int nE,
    int* __restrict__ off, int* __restrict__ cur)
{
    __shared__ int sh[256];
    int tid = threadIdx.x;
    int base = blockIdx.x * 1024 + tid * 4;
    int c[4]; int s = 0;
    #pragma unroll
    for (int k = 0; k < 4; ++k) { int i = base + k; c[k] = (i < n) ? cnt[i] : 0; s += c[k]; }
    sh[tid] = s;
    __syncthreads();
    int own = s;
    for (int offv = 1; offv < 256; offv <<= 1) {
        int t = (tid >= offv) ? sh[tid - offv] : 0;
        __syncthreads();
        sh[tid] += t;
        __syncthreads();
    }
    int excl = sh[tid] - own + part[blockIdx.x];
    #pragma unroll
    for (int k = 0; k < 4; ++k) {
        int i = base + k;
        if (i < n) { off[i] = excl; cur[i] = excl; excl += c[k]; }
    }
    if (blockIdx.x == 0 && tid == 0) off[n] = nE;
}

__global__ __launch_bounds__(256) void k_scatter(
    const int* __restrict__ src, const int* __restrict__ dst, int nE,
    int* __restrict__ cur, int* __restrict__ esrc)
{
    int i = blockIdx.x * 256 + threadIdx.x;
    if (i < nE) {
        int pos = atomicAdd(&cur[dst[i]], 1);
        esrc[pos] = src[i];
    }
}

// ---------------------------------------------------------------------------
// k_aggregate: one wave per dst, lane owns 2 cols. Pull over CSR edges.
// ---------------------------------------------------------------------------
__global__ __launch_bounds__(256) void k_aggregate(
    const int* __restrict__ off, const int* __restrict__ esrc,
    const float* __restrict__ el, const float* __restrict__ er,
    const float* __restrict__ fs, const float* __restrict__ resid,
    const float* __restrict__ conv_b, int ia, int ib, int ic,
    float* __restrict__ val)
{
    const int d = blockIdx.x * 4 + (threadIdx.x >> 6);
    const int lane = threadIdx.x & 63;
    const int h = lane >> 3;
    const int beg = off[d], end = off[d + 1];
    const float erh = er ? er[(size_t)d * NH + h] : 0.f;

    float ax = 0.f, ay = 0.f, wsum = 0.f;
    for (int base = beg; base < end; base += 64) {
        int myS = (base + lane < end) ? esrc[base + lane] : 0;  // coalesced
        int cnt = min(64, end - base);
        for (int i = 0; i < cnt; ++i) {
            int s = __shfl(myS, i);
            float e = el[(size_t)s * NH + h] + erh;
            e = (e > 0.f) ? e : NEG * e;
            float w = expf(e);
            float2 f2 = ((const float2*)(fs + (size_t)s * EMB))[lane];
            ax = fmaf(w, f2.x, ax);
            ay = fmaf(w, f2.y, ay);
            wsum += w;
        }
    }

    float vx = 0.f, vy = 0.f;
    if (end > beg) { float inv = 1.f / wsum; vx = ax * inv; vy = ay * inv; }
    if (resid) {
        float2 r = ((const float2*)(resid + (size_t)d * EMB))[lane];
        vx += r.x; vy += r.y;
    }
    const int c = lane * 2;
    float b0 = conv_b[ia * EMB + c]     + conv_b[ib * EMB + c];
    float b1 = conv_b[ia * EMB + c + 1] + conv_b[ib * EMB + c + 1];
    if (ic >= 0) { b0 += conv_b[ic * EMB + c]; b1 += conv_b[ic * EMB + c + 1]; }
    float2 o; o.x = vx + b0; o.y = vy + b1;
    ((float2*)(val + (size_t)d * EMB))[lane] = o;
}

// ---------------------------------------------------------------------------
// k_mlp64: hidden layer y = relu(val@W1 + b1), column sums into mean[].
// 64-row tile, 8x4 register tiling, LDS tree reduce, one atomic per col/block.
// ---------------------------------------------------------------------------
__global__ __launch_bounds__(256) void k_mlp64(
    const float* __restrict__ val, int nrows,
    const float* __restrict__ rw1, const float* __restrict__ rb1,
    float* __restrict__ mean)
{
    __shared__ float xs[TILE][LPAD];   // 33 KB
    __shared__ float red[8][EMB];      // 4 KB

    const int tid = threadIdx.x;
    const int nbase = blockIdx.x * TILE;

    #pragma unroll
    for (int r = 0; r < 8; ++r) {
        int f4 = r * 256 + tid;
        int t  = f4 >> 5;
        int c4 = f4 & 31;
        int row = nbase + t;
        if (row < nrows)
            ((float4*)&xs[t][0])[c4] =
                ((const float4*)(val + (size_t)row * EMB))[c4];
    }
    __syncthreads();

    const int cg = tid & 31;
    const int rg = tid >> 5;
    const int j0 = cg * 4;
    const float* W = rw1 + j0;

    float a[8][4];
    #pragma unroll
    for (int r = 0; r < 8; ++r)
        #pragma unroll
        for (int c = 0; c < 4; ++c) a[r][c] = 0.f;

    for (int k = 0; k < EMB; k += 4) {
        float wv[4][4];
        #pragma unroll
        for (int kk = 0; kk < 4; ++kk) {
            float4 t0 = *((const float4*)(W + (size_t)(k + kk) * EMB));
            wv[kk][0] = t0.x; wv[kk][1] = t0.y; wv[kk][2] = t0.z; wv[kk][3] = t0.w;
        }
        #pragma unroll
        for (int r = 0; r < 8; ++r) {
            float4 x = *((const float4*)&xs[rg * 8 + r][k]);
            #pragma unroll
            for (int c = 0; c < 4; ++c) {
                a[r][c] = fmaf(x.x, wv[0][c], a[r][c]);
                a[r][c] = fmaf(x.y, wv[1][c], a[r][c]);
                a[r][c] = fmaf(x.z, wv[2][c], a[r][c]);
                a[r][c] = fmaf(x.w, wv[3][c], a[r][c]);
            }
        }
    }

    // relu + per-thread column sums over valid rows
    float b1v[4];
    #pragma unroll
    for (int c = 0; c < 4; ++c) b1v[c] = rb1[j0 + c];
    float cs[4] = {0.f, 0.f, 0.f, 0.f};
    #pragma unroll
    for (int r = 0; r < 8; ++r) {
        int row = nbase + rg * 8 + r;
        if (row < nrows) {
            #pragma unroll
            for (int c = 0; c < 4; ++c)
                cs[c] += fmaxf(a[r][c] + b1v[c], 0.f);
        }
    }
    *((float4*)&red[rg][j0]) = make_float4(cs[0], cs[1], cs[2], cs[3]);
    __syncthreads();
    if (tid < EMB) {
        float s = 0.f;
        #pragma unroll
        for (int g = 0; g < 8; ++g) s += red[g][tid];
        atomicAdd(mean + tid, s);
    }
}

// ---------------------------------------------------------------------------
// k_final: second MLP layers on the column means + constant gran3 row +
// softmax(gran_w) + fused output.
// ---------------------------------------------------------------------------
__global__ __launch_bounds__(128) void k_final(
    const float* __restrict__ mean1, const float* __restrict__ mean2,
    const float* __restrict__ conv_b,
    const float* __restrict__ r_w1, const float* __restrict__ r_b1,
    const float* __restrict__ r_w2, const float* __restrict__ r_b2,
    const float* __restrict__ gran_w, float* __restrict__ out)
{
    __shared__ float m1[EMB], m2[EMB], x3[EMB], t3[EMB];
    const int j = threadIdx.x;
    m1[j] = mean1[j] * (1.f / N1);
    m2[j] = mean2[j] * (1.f / N2);
    x3[j] = conv_b[2 * EMB + j] + conv_b[5 * EMB + j];
    __syncthreads();

    float a = r_b1[2 * EMB + j];
    for (int k = 0; k < EMB; ++k)
        a = fmaf(x3[k], r_w1[2 * EMB * EMB + k * EMB + j], a);
    t3[j] = fmaxf(a, 0.f);
    __syncthreads();

    float r1 = r_b2[0 * EMB + j];
    float r2 = r_b2[1 * EMB + j];
    float r3 = r_b2[2 * EMB + j];
    for (int k = 0; k < EMB; ++k) {
        r1 = fmaf(m1[k], r_w2[0 * EMB * EMB + k * EMB + j], r1);
        r2 = fmaf(m2[k], r_w2[1 * EMB * EMB + k * EMB + j], r2);
        r3 = fmaf(t3[k], r_w2[2 * EMB * EMB + k * EMB + j], r3);
    }

    float g0 = gran_w[0], g1 = gran_w[1], g2 = gran_w[2];
    float mx = fmaxf(g0, fmaxf(g1, g2));
    float e0 = expf(g0 - mx), e1 = expf(g1 - mx), e2 = expf(g2 - mx);
    float s = e0 + e1 + e2;
    float w0 = e0 / s, w1 = e1 / s, w2 = e2 / s;

    out[j]       = w0 * r1 + w1 * r2 + w2 * r3;
    out[128 + j] = r1;
    out[256 + j] = r2;
    out[384 + j] = r3;
    if (j < 3) out[512 + j] = (j == 0) ? w0 : (j == 1) ? w1 : w2;
}

extern "C" void kernel_launch(void* const* d_in, const int* in_sizes, int n_in,
                              void* d_out, int out_size, void* d_ws, size_t ws_size,
                              hipStream_t stream) {
    const int*   item_ids = (const int*)d_in[0];
    const int*   s1s = (const int*)d_in[1];
    const int*   s1d = (const int*)d_in[2];
    const int*   u1s = (const int*)d_in[7];
    const int*   u1d = (const int*)d_in[8];
    const float* item_emb = (const float*)d_in[15];
    const float* fc_w   = (const float*)d_in[16];
    const float* attn_l = (const float*)d_in[17];
    const float* attn_r = (const float*)d_in[18];
    const float* conv_b = (const float*)d_in[19];
    const float* r_w1 = (const float*)d_in[20];
    const float* r_b1 = (const float*)d_in[21];
    const float* r_w2 = (const float*)d_in[22];
    const float* r_b2 = (const float*)d_in[23];
    const float* gran_w = (const float*)d_in[24];

    const int nE1 = in_sizes[1];   // 600000
    const int nE3 = in_sizes[7];   // 200000

    float* ws = (float*)d_ws;
    // --- zero region (one memset): mean1 | mean2 | cnt1 | cnt2
    float* mean1 = ws;
    float* mean2 = mean1 + EMB;
    int*   cnt1  = (int*)(mean2 + EMB);
    int*   cnt2  = cnt1 + N1;
    size_t zeroN = 2 * EMB + N1 + N2;
    // --- non-zeroed scratch
    int*   off1  = cnt2 + N2;            // N1+1
    int*   cur1  = off1 + N1 + 1;        // N1
    int*   off2  = cur1 + N1;            // N2+1
    int*   cur2  = off2 + N2 + 1;        // N2
    int*   part1 = cur2 + N2;            // 128
    int*   part2 = part1 + 128;          // 128
    int*   esrc1 = part2 + 128;          // nE1
    int*   esrc2 = esrc1 + nE1;          // nE3
    float* h1   = (float*)(esrc2 + nE3); // N1*128
    float* fs0  = h1  + (size_t)N1 * EMB;
    float* fs3  = fs0 + (size_t)N1 * EMB;
    float* el0  = fs3 + (size_t)N1 * EMB;  // N1*8
    float* er0  = el0 + (size_t)N1 * NH;
    float* el3  = er0 + (size_t)N1 * NH;
    float* val1 = el3 + (size_t)N1 * NH;   // N1*128
    float* val2 = val1 + (size_t)N1 * EMB; // N2*128

    hipMemsetAsync(ws, 0, zeroN * sizeof(float), stream);

    // features + attention dots (fused epilogue)
    k_feat64<<<(N1 + TILE - 1) / TILE, 256, 0, stream>>>(
        item_emb, item_ids, fc_w, attn_l, attn_r, h1, fs0, fs3, el0, er0, el3);

    // CSR build, graph seq1 (dst domain N1)
    const int nch1 = (N1 + 1023) / 1024;   // 98
    k_count<<<(nE1 + 255) / 256, 256, 0, stream>>>(s1d, nE1, cnt1);
    k_scan_partial<<<nch1, 256, 0, stream>>>(cnt1, N1, part1);
    k_scan_mid<<<1, 256, 0, stream>>>(part1, nch1);
    k_scan_final<<<nch1, 256, 0, stream>>>(cnt1, part1, N1, nE1, off1, cur1);
    k_scatter<<<(nE1 + 255) / 256, 256, 0, stream>>>(s1s, s1d, nE1, cur1, esrc1);

    // CSR build, graph up1 (dst domain N2)
    const int nch2 = (N2 + 1023) / 1024;   // 20
    k_count<<<(nE3 + 255) / 256, 256, 0, stream>>>(u1d, nE3, cnt2);
    k_scan_partial<<<nch2, 256, 0, stream>>>(cnt2, N2, part2);
    k_scan_mid<<<1, 256, 0, stream>>>(part2, nch2);
    k_scan_final<<<nch2, 256, 0, stream>>>(cnt2, part2, N2, nE3, off2, cur2);
    k_scatter<<<(nE3 + 255) / 256, 256, 0, stream>>>(u1s, u1d, nE3, cur2, esrc2);

    // pull aggregation (writes fully assembled rows)
    k_aggregate<<<N1 / 4, 256, 0, stream>>>(off1, esrc1, el0, er0, fs0, h1,
                                            conv_b, 0, 4, -1, val1);
    k_aggregate<<<N2 / 4, 256, 0, stream>>>(off2, esrc2, el3, nullptr, fs3, nullptr,
                                            conv_b, 3, 1, 6, val2);

    // hidden MLP + column-sum reduction
    k_mlp64<<<(N1 + TILE - 1) / TILE, 256, 0, stream>>>(
        val1, N1, r_w1 + 0 * EMB * EMB, r_b1 + 0 * EMB, mean1);
    k_mlp64<<<(N2 + TILE - 1) / TILE, 256, 0, stream>>>(
        val2, N2, r_w1 + 1 * EMB * EMB, r_b1 + 1 * EMB, mean2);

    k_final<<<1, 128, 0, stream>>>(mean1, mean2, conv_b, r_w1, r_b1, r_w2, r_b2,
                                   gran_w, (float*)d_out);
}

// Round 6
// 560.361 us; speedup vs baseline: 2.4807x; 1.0443x over previous
//
#include <hip/hip_runtime.h>
#include <math.h>

#define N1 100000
#define N2 20000
#define EMB 128
#define NH 8
#define TILE 64
#define LPAD 132   // LDS row pitch (floats): 132 ≡ 4 (mod 32) banks, 16B-aligned

static constexpr float NEG = 0.2f;

// compile-time float4 component select (c must be a constant after unroll)
#define F4C(v, c) ((c) == 0 ? (v).x : (c) == 1 ? (v).y : (c) == 2 ? (v).z : (v).w)

// ---------------------------------------------------------------------------
// k_feat64: gather item_emb[item_ids] into LDS (64-row tile), dual GEMM
// fs0 = h1@W0, fs3 = h1@W3 with 8x4 register tiling and SOFTWARE-PIPELINED
// weight loads (double-buffered next k-quad), fused attention-dot epilogue.
// 256 threads: cg = tid&31 owns cols 4cg..+3, rg = tid>>5 owns rows 8rg..+7.
// ---------------------------------------------------------------------------
__global__ __launch_bounds__(256) void k_feat64(
    const float* __restrict__ item_emb, const int* __restrict__ item_ids,
    const float* __restrict__ fc_w, const float* __restrict__ attn_l,
    const float* __restrict__ attn_r,
    float* __restrict__ fs0, float* __restrict__ fs3,
    float* __restrict__ el0, float* __restrict__ er0, float* __restrict__ el3)
{
    __shared__ float xs[TILE][LPAD];   // 33 KB

    const int tid = threadIdx.x;
    const int nbase = blockIdx.x * TILE;

    // gather: 64 rows x 32 float4, 8 per thread
    #pragma unroll
    for (int r = 0; r < 8; ++r) {
        int f4 = r * 256 + tid;
        int t  = f4 >> 5;
        int c4 = f4 & 31;
        int node = nbase + t;
        if (node < N1) {
            int row = item_ids[node];
            ((float4*)&xs[t][0])[c4] =
                ((const float4*)(item_emb + (size_t)row * EMB))[c4];
        }
    }
    __syncthreads();

    const int cg = tid & 31;
    const int rg = tid >> 5;
    const int j0 = cg * 4;
    const float* W0 = fc_w + j0;
    const float* W3 = fc_w + 3 * EMB * EMB + j0;

    float a0[8][4], a3[8][4];
    #pragma unroll
    for (int r = 0; r < 8; ++r)
        #pragma unroll
        for (int c = 0; c < 4; ++c) { a0[r][c] = 0.f; a3[r][c] = 0.f; }

    // double-buffered weight quads
    float4 wc0[4], wc3[4], wn0[4], wn3[4];
    #pragma unroll
    for (int kk = 0; kk < 4; ++kk) {
        wc0[kk] = *((const float4*)(W0 + (size_t)kk * EMB));
        wc3[kk] = *((const float4*)(W3 + (size_t)kk * EMB));
    }

    for (int k = 0; k < EMB; k += 4) {
        const int kn = k + 4;
        if (kn < EMB) {
            #pragma unroll
            for (int kk = 0; kk < 4; ++kk) {
                wn0[kk] = *((const float4*)(W0 + (size_t)(kn + kk) * EMB));
                wn3[kk] = *((const float4*)(W3 + (size_t)(kn + kk) * EMB));
            }
        }
        #pragma unroll
        for (int r = 0; r < 8; ++r) {
            float4 x = *((const float4*)&xs[rg * 8 + r][k]);
            #pragma unroll
            for (int c = 0; c < 4; ++c) {
                float acc0 = a0[r][c], acc3 = a3[r][c];
                acc0 = fmaf(x.x, F4C(wc0[0], c), acc0);
                acc0 = fmaf(x.y, F4C(wc0[1], c), acc0);
                acc0 = fmaf(x.z, F4C(wc0[2], c), acc0);
                acc0 = fmaf(x.w, F4C(wc0[3], c), acc0);
                acc3 = fmaf(x.x, F4C(wc3[0], c), acc3);
                acc3 = fmaf(x.y, F4C(wc3[1], c), acc3);
                acc3 = fmaf(x.z, F4C(wc3[2], c), acc3);
                acc3 = fmaf(x.w, F4C(wc3[3], c), acc3);
                a0[r][c] = acc0; a3[r][c] = acc3;
            }
        }
        if (kn < EMB) {
            #pragma unroll
            for (int kk = 0; kk < 4; ++kk) { wc0[kk] = wn0[kk]; wc3[kk] = wn3[kk]; }
        }
    }

    // store fs tiles
    #pragma unroll
    for (int r = 0; r < 8; ++r) {
        int row = nbase + rg * 8 + r;
        if (row < N1) {
            float4 v0 = make_float4(a0[r][0], a0[r][1], a0[r][2], a0[r][3]);
            float4 v3 = make_float4(a3[r][0], a3[r][1], a3[r][2], a3[r][3]);
            *((float4*)(fs0 + (size_t)row * EMB + j0)) = v0;
            *((float4*)(fs3 + (size_t)row * EMB + j0)) = v3;
        }
    }

    // fused attention dots: head = j0>>4; 4-lane shfl_xor completes the dot
    float al0v[4], ar0v[4], al3v[4];
    #pragma unroll
    for (int c = 0; c < 4; ++c) {
        al0v[c] = attn_l[j0 + c];
        ar0v[c] = attn_r[j0 + c];
        al3v[c] = attn_l[3 * EMB + j0 + c];
    }
    const int head = j0 >> 4;
    #pragma unroll
    for (int r = 0; r < 8; ++r) {
        float pe = a0[r][0]*al0v[0] + a0[r][1]*al0v[1] + a0[r][2]*al0v[2] + a0[r][3]*al0v[3];
        float pr = a0[r][0]*ar0v[0] + a0[r][1]*ar0v[1] + a0[r][2]*ar0v[2] + a0[r][3]*ar0v[3];
        float p3 = a3[r][0]*al3v[0] + a3[r][1]*al3v[1] + a3[r][2]*al3v[2] + a3[r][3]*al3v[3];
        pe += __shfl_xor(pe, 1); pe += __shfl_xor(pe, 2);
        pr += __shfl_xor(pr, 1); pr += __shfl_xor(pr, 2);
        p3 += __shfl_xor(p3, 1); p3 += __shfl_xor(p3, 2);
        int row = nbase + rg * 8 + r;
        if ((cg & 3) == 0 && row < N1) {
            el0[(size_t)row * NH + head] = pe;
            er0[(size_t)row * NH + head] = pr;
            el3[(size_t)row * NH + head] = p3;
        }
    }
}

// ---------------------------------------------------------------------------
// merged CSR build over combined dst domain [0,N1) ∪ [N1,N1+N2)
// ---------------------------------------------------------------------------
__global__ __launch_bounds__(256) void k_count2(
    const int* __restrict__ s1d, int nE1,
    const int* __restrict__ u1d, int nE3, int* __restrict__ cnt)
{
    int i = blockIdx.x * 256 + threadIdx.x;
    if (i < nE1) atomicAdd(&cnt[s1d[i]], 1);
    else if (i < nE1 + nE3) atomicAdd(&cnt[N1 + u1d[i - nE1]], 1);
}

__global__ __launch_bounds__(256) void k_scan_partial(
    const int* __restrict__ cnt, int n, int* __restrict__ part)
{
    __shared__ int sh[256];
    int base = blockIdx.x * 1024 + threadIdx.x * 4;
    int s = 0;
    #pragma unroll
    for (int k = 0; k < 4; ++k) { int i = base + k; if (i < n) s += cnt[i]; }
    sh[threadIdx.x] = s;
    __syncthreads();
    for (int off = 128; off > 0; off >>= 1) {
        if (threadIdx.x < off) sh[threadIdx.x] += sh[threadIdx.x + off];
        __syncthreads();
    }
    if (threadIdx.x == 0) part[blockIdx.x] = sh[0];
}

__global__ __launch_bounds__(256) void k_scan_mid(int* part, int np)
{
    __shared__ int sh[256];
    int tid = threadIdx.x;
    int v = (tid < np) ? part[tid] : 0;
    sh[tid] = v;
    __syncthreads();
    for (int off = 1; off < 256; off <<= 1) {
        int t = (tid >= off) ? sh[tid - off] : 0;
        __syncthreads();
        sh[tid] += t;
        __syncthreads();
    }
    if (tid < np) part[tid] = sh[tid] - v;   // exclusive
}

__global__ __launch_bounds__(256) void k_scan_final(
    const int* __restrict__ cnt, const int* __restrict__ part, int n, int nE,
    int* __restrict__ off, int* __restrict__ cur)
{
    __shared__ int sh[256];
    int tid = threadIdx.x;
    int base = blockIdx.x * 1024 + tid * 4;
    int c[4]; int s = 0;
    #pragma unroll
    for (int k = 0; k < 4; ++k) { int i = base + k; c[k] = (i < n) ? cnt[i] : 0; s += c[k]; }
    sh[tid] = s;
    __syncthreads();
    int own = s;
    for (int offv = 1; offv < 256; offv <<= 1) {
        int t = (tid >= offv) ? sh[tid - offv] : 0;
        __syncthreads();
        sh[tid] += t;
        __syncthreads();
    }
    int excl = sh[tid] - own + part[blockIdx.x];
    #pragma unroll
    for (int k = 0; k < 4; ++k) {
        int i = base + k;
        if (i < n) { off[i] = excl; cur[i] = excl; excl += c[k]; }
    }
    if (blockIdx.x == 0 && tid == 0) off[n] = nE;
}

__global__ __launch_bounds__(256) void k_scatter2(
    const int* __restrict__ s1s, const int* __restrict__ s1d, int nE1,
    const int* __restrict__ u1s, const int* __restrict__ u1d, int nE3,
    int* __restrict__ cur, int* __restrict__ esrc)
{
    int i = blockIdx.x * 256 + threadIdx.x;
    if (i < nE1) {
        int pos = atomicAdd(&cur[s1d[i]], 1);
        esrc[pos] = s1s[i];
    } else if (i < nE1 + nE3) {
        int j = i - nE1;
        int pos = atomicAdd(&cur[N1 + u1d[j]], 1);
        esrc[pos] = u1s[j];
    }
}

// ---------------------------------------------------------------------------
// k_agg: merged pull aggregation over combined CSR. One wave per dst, lane
// owns 2 cols. wid<N1 -> graph seq1 (el0/er0/fs0, resid=item_emb gather,
// bias b0+b4 -> val1); else -> graph up1 (el3/fs3, bias b3+b1+b6 -> val2).
// Inner loop unrolled x2, __expf. Zero float atomics.
// ---------------------------------------------------------------------------
__global__ __launch_bounds__(256) void k_agg(
    const int* __restrict__ off, const int* __restrict__ esrc,
    const float* __restrict__ el0, const float* __restrict__ er0,
    const float* __restrict__ fs0,
    const float* __restrict__ el3, const float* __restrict__ fs3,
    const float* __restrict__ item_emb, const int* __restrict__ item_ids,
    const float* __restrict__ conv_b,
    float* __restrict__ val1, float* __restrict__ val2)
{
    const int wid  = blockIdx.x * 4 + (threadIdx.x >> 6);
    const int lane = threadIdx.x & 63;
    const int h = lane >> 3;
    const int c = lane * 2;

    const float* el; const float* fs;
    float erh, b0, b1;
    bool g1 = (wid < N1);
    if (g1) {
        el = el0; fs = fs0;
        erh = er0[(size_t)wid * NH + h];
        b0 = conv_b[0 * EMB + c]     + conv_b[4 * EMB + c];
        b1 = conv_b[0 * EMB + c + 1] + conv_b[4 * EMB + c + 1];
    } else {
        el = el3; fs = fs3;
        erh = 0.f;
        b0 = conv_b[3 * EMB + c]     + conv_b[1 * EMB + c]     + conv_b[6 * EMB + c];
        b1 = conv_b[3 * EMB + c + 1] + conv_b[1 * EMB + c + 1] + conv_b[6 * EMB + c + 1];
    }

    const int beg = off[wid], end = off[wid + 1];
    float ax = 0.f, ay = 0.f, wsum = 0.f;
    for (int base = beg; base < end; base += 64) {
        int myS = (base + lane < end) ? esrc[base + lane] : 0;  // coalesced
        int cnt = min(64, end - base);
        int i = 0;
        for (; i + 1 < cnt; i += 2) {
            int sA = __shfl(myS, i);
            int sB = __shfl(myS, i + 1);
            float eA = el[(size_t)sA * NH + h] + erh;
            float eB = el[(size_t)sB * NH + h] + erh;
            eA = (eA > 0.f) ? eA : NEG * eA;
            eB = (eB > 0.f) ? eB : NEG * eB;
            float wA = __expf(eA);
            float wB = __expf(eB);
            float2 fA = ((const float2*)(fs + (size_t)sA * EMB))[lane];
            float2 fB = ((const float2*)(fs + (size_t)sB * EMB))[lane];
            ax = fmaf(wA, fA.x, fmaf(wB, fB.x, ax));
            ay = fmaf(wA, fA.y, fmaf(wB, fB.y, ay));
            wsum += wA + wB;
        }
        if (i < cnt) {
            int s = __shfl(myS, i);
            float e = el[(size_t)s * NH + h] + erh;
            e = (e > 0.f) ? e : NEG * e;
            float w = __expf(e);
            float2 f2 = ((const float2*)(fs + (size_t)s * EMB))[lane];
            ax = fmaf(w, f2.x, ax);
            ay = fmaf(w, f2.y, ay);
            wsum += w;
        }
    }

    float vx = 0.f, vy = 0.f;
    if (end > beg) { float inv = 1.f / wsum; vx = ax * inv; vy = ay * inv; }
    if (g1) {
        float2 r = ((const float2*)(item_emb + (size_t)item_ids[wid] * EMB))[lane];
        vx += r.x; vy += r.y;
    }
    float2 o; o.x = vx + b0; o.y = vy + b1;
    float* out = g1 ? (val1 + (size_t)wid * EMB) : (val2 + (size_t)(wid - N1) * EMB);
    ((float2*)out)[lane] = o;
}

// ---------------------------------------------------------------------------
// k_mlp64: hidden layer y = relu(val@W1 + b1), column sums into mean[].
// 64-row tile, 8x4 register tiling, double-buffered weight loads.
// ---------------------------------------------------------------------------
__global__ __launch_bounds__(256) void k_mlp64(
    const float* __restrict__ val, int nrows,
    const float* __restrict__ rw1, const float* __restrict__ rb1,
    float* __restrict__ mean)
{
    __shared__ float xs[TILE][LPAD];   // 33 KB
    __shared__ float red[8][EMB];      // 4 KB

    const int tid = threadIdx.x;
    const int nbase = blockIdx.x * TILE;

    #pragma unroll
    for (int r = 0; r < 8; ++r) {
        int f4 = r * 256 + tid;
        int t  = f4 >> 5;
        int c4 = f4 & 31;
        int row = nbase + t;
        if (row < nrows)
            ((float4*)&xs[t][0])[c4] =
                ((const float4*)(val + (size_t)row * EMB))[c4];
    }
    __syncthreads();

    const int cg = tid & 31;
    const int rg = tid >> 5;
    const int j0 = cg * 4;
    const float* W = rw1 + j0;

    float a[8][4];
    #pragma unroll
    for (int r = 0; r < 8; ++r)
        #pragma unroll
        for (int c = 0; c < 4; ++c) a[r][c] = 0.f;

    float4 wc[4], wn[4];
    #pragma unroll
    for (int kk = 0; kk < 4; ++kk) wc[kk] = *((const float4*)(W + (size_t)kk * EMB));

    for (int k = 0; k < EMB; k += 4) {
        const int kn = k + 4;
        if (kn < EMB) {
            #pragma unroll
            for (int kk = 0; kk < 4; ++kk)
                wn[kk] = *((const float4*)(W + (size_t)(kn + kk) * EMB));
        }
        #pragma unroll
        for (int r = 0; r < 8; ++r) {
            float4 x = *((const float4*)&xs[rg * 8 + r][k]);
            #pragma unroll
            for (int c = 0; c < 4; ++c) {
                float acc = a[r][c];
                acc = fmaf(x.x, F4C(wc[0], c), acc);
                acc = fmaf(x.y, F4C(wc[1], c), acc);
                acc = fmaf(x.z, F4C(wc[2], c), acc);
                acc = fmaf(x.w, F4C(wc[3], c), acc);
                a[r][c] = acc;
            }
        }
        if (kn < EMB) {
            #pragma unroll
            for (int kk = 0; kk < 4; ++kk) wc[kk] = wn[kk];
        }
    }

    float b1v[4];
    #pragma unroll
    for (int c = 0; c < 4; ++c) b1v[c] = rb1[j0 + c];
    float cs[4] = {0.f, 0.f, 0.f, 0.f};
    #pragma unroll
    for (int r = 0; r < 8; ++r) {
        int row = nbase + rg * 8 + r;
        if (row < nrows) {
            #pragma unroll
            for (int c = 0; c < 4; ++c)
                cs[c] += fmaxf(a[r][c] + b1v[c], 0.f);
        }
    }
    *((float4*)&red[rg][j0]) = make_float4(cs[0], cs[1], cs[2], cs[3]);
    __syncthreads();
    if (tid < EMB) {
        float s = 0.f;
        #pragma unroll
        for (int g = 0; g < 8; ++g) s += red[g][tid];
        atomicAdd(mean + tid, s);
    }
}

// ---------------------------------------------------------------------------
// k_final: second MLP layers on the column means + constant gran3 row +
// softmax(gran_w) + fused output.
// ---------------------------------------------------------------------------
__global__ __launch_bounds__(128) void k_final(
    const float* __restrict__ mean1, const float* __restrict__ mean2,
    const float* __restrict__ conv_b,
    const float* __restrict__ r_w1, const float* __restrict__ r_b1,
    const float* __restrict__ r_w2, const float* __restrict__ r_b2,
    const float* __restrict__ gran_w, float* __restrict__ out)
{
    __shared__ float m1[EMB], m2[EMB], x3[EMB], t3[EMB];
    const int j = threadIdx.x;
    m1[j] = mean1[j] * (1.f / N1);
    m2[j] = mean2[j] * (1.f / N2);
    x3[j] = conv_b[2 * EMB + j] + conv_b[5 * EMB + j];
    __syncthreads();

    float a = r_b1[2 * EMB + j];
    for (int k = 0; k < EMB; ++k)
        a = fmaf(x3[k], r_w1[2 * EMB * EMB + k * EMB + j], a);
    t3[j] = fmaxf(a, 0.f);
    __syncthreads();

    float r1 = r_b2[0 * EMB + j];
    float r2 = r_b2[1 * EMB + j];
    float r3 = r_b2[2 * EMB + j];
    for (int k = 0; k < EMB; ++k) {
        r1 = fmaf(m1[k], r_w2[0 * EMB * EMB + k * EMB + j], r1);
        r2 = fmaf(m2[k], r_w2[1 * EMB * EMB + k * EMB + j], r2);
        r3 = fmaf(t3[k], r_w2[2 * EMB * EMB + k * EMB + j], r3);
    }

    float g0 = gran_w[0], g1 = gran_w[1], g2 = gran_w[2];
    float mx = fmaxf(g0, fmaxf(g1, g2));
    float e0 = expf(g0 - mx), e1 = expf(g1 - mx), e2 = expf(g2 - mx);
    float s = e0 + e1 + e2;
    float w0 = e0 / s, w1 = e1 / s, w2 = e2 / s;

    out[j]       = w0 * r1 + w1 * r2 + w2 * r3;
    out[128 + j] = r1;
    out[256 + j] = r2;
    out[384 + j] = r3;
    if (j < 3) out[512 + j] = (j == 0) ? w0 : (j == 1) ? w1 : w2;
}

extern "C" void kernel_launch(void* const* d_in, const int* in_sizes, int n_in,
                              void* d_out, int out_size, void* d_ws, size_t ws_size,
                              hipStream_t stream) {
    const int*   item_ids = (const int*)d_in[0];
    const int*   s1s = (const int*)d_in[1];
    const int*   s1d = (const int*)d_in[2];
    const int*   u1s = (const int*)d_in[7];
    const int*   u1d = (const int*)d_in[8];
    const float* item_emb = (const float*)d_in[15];
    const float* fc_w   = (const float*)d_in[16];
    const float* attn_l = (const float*)d_in[17];
    const float* attn_r = (const float*)d_in[18];
    const float* conv_b = (const float*)d_in[19];
    const float* r_w1 = (const float*)d_in[20];
    const float* r_b1 = (const float*)d_in[21];
    const float* r_w2 = (const float*)d_in[22];
    const float* r_b2 = (const float*)d_in[23];
    const float* gran_w = (const float*)d_in[24];

    const int nE1 = in_sizes[1];   // 600000
    const int nE3 = in_sizes[7];   // 200000
    const int nEt = nE1 + nE3;
    const int ND  = N1 + N2;       // combined dst domain

    float* ws = (float*)d_ws;
    // --- zero region (one memset): mean1 | mean2 | cnt (combined)
    float* mean1 = ws;
    float* mean2 = mean1 + EMB;
    int*   cnt   = (int*)(mean2 + EMB);      // ND
    size_t zeroN = 2 * EMB + ND;
    // --- non-zeroed scratch (keep 16B alignment for the float4 arrays)
    int*   off   = cnt + ND;                 // ND+1 (padded to ND+4)
    int*   cur   = off + ND + 4;             // ND
    int*   part  = cur + ND;                 // 128 (need 118)
    int*   esrc  = part + 128;               // nEt (800000, %4==0)
    float* fs0   = (float*)(esrc + nEt);     // N1*128
    float* fs3   = fs0 + (size_t)N1 * EMB;   // N1*128
    float* el0   = fs3 + (size_t)N1 * EMB;   // N1*8
    float* er0   = el0 + (size_t)N1 * NH;    // N1*8
    float* el3   = er0 + (size_t)N1 * NH;    // N1*8
    float* val1  = el3 + (size_t)N1 * NH;    // N1*128
    float* val2  = val1 + (size_t)N1 * EMB;  // N2*128

    hipMemsetAsync(ws, 0, zeroN * sizeof(float), stream);

    // features + attention dots (pipelined dual GEMM, no h1 materialization)
    k_feat64<<<(N1 + TILE - 1) / TILE, 256, 0, stream>>>(
        item_emb, item_ids, fc_w, attn_l, attn_r, fs0, fs3, el0, er0, el3);

    // merged CSR build over combined dst domain
    const int nch = (ND + 1023) / 1024;      // 118
    k_count2<<<(nEt + 255) / 256, 256, 0, stream>>>(s1d, nE1, u1d, nE3, cnt);
    k_scan_partial<<<nch, 256, 0, stream>>>(cnt, ND, part);
    k_scan_mid<<<1, 256, 0, stream>>>(part, nch);
    k_scan_final<<<nch, 256, 0, stream>>>(cnt, part, ND, nEt, off, cur);
    k_scatter2<<<(nEt + 255) / 256, 256, 0, stream>>>(s1s, s1d, nE1,
                                                      u1s, u1d, nE3, cur, esrc);

    // merged pull aggregation (writes fully assembled rows)
    k_agg<<<ND / 4, 256, 0, stream>>>(off, esrc, el0, er0, fs0, el3, fs3,
                                      item_emb, item_ids, conv_b, val1, val2);

    // hidden MLP + column-sum reduction
    k_mlp64<<<(N1 + TILE - 1) / TILE, 256, 0, stream>>>(
        val1, N1, r_w1 + 0 * EMB * EMB, r_b1 + 0 * EMB, mean1);
    k_mlp64<<<(N2 + TILE - 1) / TILE, 256, 0, stream>>>(
        val2, N2, r_w1 + 1 * EMB * EMB, r_b1 + 1 * EMB, mean2);

    k_final<<<1, 128, 0, stream>>>(mean1, mean2, conv_b, r_w1, r_b1, r_w2, r_b2,
                                   gran_w, (float*)d_out);
}